// Round 1
// baseline (864.820 us; speedup 1.0000x reference)
//
#include <hip/hip_runtime.h>

#define FEAT   512
#define MEMN   256
#define BATCH  512
#define PROMPT 131072   // 64*2048 flattened
#define TOPK   16
#define EPSF   1e-8f

// ctx kernel tiling
#define COLS   64                 // columns per block (LDS slab width)
#define BT     64                 // batches per block tile
#define CHUNKS (PROMPT / COLS)    // 2048
#define TILES  (BATCH / BT)       // 8

// ---------------------------------------------------------------------------
// Kernel A: cosine sim (512 x 256) + top-16 + clamped/renormalized weights.
// One block per batch sample; thread m computes sim[m]; wave 0 does top-k.
// ---------------------------------------------------------------------------
__global__ __launch_bounds__(256) void topk_kernel(
    const float* __restrict__ features,
    const float* __restrict__ keys,
    int* __restrict__ out_ids,
    float* __restrict__ out_w)
{
    __shared__ float f_lds[FEAT];
    __shared__ float sim_lds[MEMN];

    const int b = blockIdx.x;
    const int tid = threadIdx.x;

    for (int j = tid; j < FEAT; j += 256)
        f_lds[j] = features[b * FEAT + j];
    __syncthreads();

    // thread m computes dot(f, k_m), |k_m|^2, |f|^2
    {
        const int m = tid;  // 256 threads == MEMN
        const float* krow = keys + m * FEAT;
        float dot = 0.f, k2 = 0.f, f2 = 0.f;
        for (int j = 0; j < FEAT; ++j) {
            const float fj = f_lds[j];
            const float kj = krow[j];
            dot += fj * kj;
            k2  += kj * kj;
            f2  += fj * fj;
        }
        float fn = sqrtf(f2); if (fn < EPSF) fn = EPSF;
        float kn = sqrtf(k2); if (kn < EPSF) kn = EPSF;
        sim_lds[m] = dot / (fn * kn);
    }
    __syncthreads();

    // single-wave top-16 (tie -> lowest index, matching jax.lax.top_k)
    if (tid < 64) {
        const int lane = tid;
        float v0 = sim_lds[lane];
        float v1 = sim_lds[lane + 64];
        float v2 = sim_lds[lane + 128];
        float v3 = sim_lds[lane + 192];
        int myid = 0;   // lane r (r<16) records round-r winner index

        for (int r = 0; r < TOPK; ++r) {
            float bv = v0; int bi = lane;
            if (v1 > bv) { bv = v1; bi = lane + 64;  }
            if (v2 > bv) { bv = v2; bi = lane + 128; }
            if (v3 > bv) { bv = v3; bi = lane + 192; }
            for (int off = 32; off > 0; off >>= 1) {
                const float ov = __shfl_down(bv, off);
                const int   oi = __shfl_down(bi, off);
                if (ov > bv || (ov == bv && oi < bi)) { bv = ov; bi = oi; }
            }
            bi = __shfl(bi, 0);           // broadcast winner index
            if (lane == r) myid = bi;
            if ((bi & 63) == lane) {      // invalidate winner's slot
                const int slot = bi >> 6;
                if      (slot == 0) v0 = -1e30f;
                else if (slot == 1) v1 = -1e30f;
                else if (slot == 2) v2 = -1e30f;
                else                v3 = -1e30f;
            }
        }

        if (lane < TOPK) {
            float val = sim_lds[myid];
            if (val < 0.f) val = 0.f;
            float s = val;
            for (int off = 1; off < TOPK; off <<= 1)
                s += __shfl_xor(s, off);      // lanes 0..15 closed under xor<16
            out_ids[b * TOPK + lane] = myid;
            out_w[b * TOPK + lane]   = val / s;
        }
    }
}

// ---------------------------------------------------------------------------
// Kernel B: ctx[b, col] = sum_k w[b,k] * mem[id[b,k], col]
// Block = (column chunk of 64, batch tile of 64). Stage all 256 memory rows'
// 64-col slab in LDS (64 KB), then each thread serves 16 batches for 1 col.
// XCD-swizzled block id: all 8 batch tiles of a column chunk land on one XCD.
// ---------------------------------------------------------------------------
__global__ __launch_bounds__(256) void ctx_kernel(
    const float* __restrict__ mem,
    const int* __restrict__ ids,
    const float* __restrict__ wgt,
    float* __restrict__ out)
{
    __shared__ float slab[MEMN * COLS];   // 64 KB
    __shared__ int   s_ids[BT * TOPK];    // 4 KB
    __shared__ float s_w[BT * TOPK];      // 4 KB

    const int bid  = blockIdx.x;
    const int xcd  = bid & 7;
    const int s    = bid >> 3;
    const int tile = s & 7;                      // batch tile 0..7
    const int chunk = ((s >> 3) << 3) | xcd;     // column chunk 0..2047
    const int col_base = chunk * COLS;
    const int b_base   = tile * BT;

    const int tid = threadIdx.x;

    // load this tile's sparse ids/weights
    for (int i = tid; i < BT * TOPK; i += 256) {
        s_ids[i] = ids[b_base * TOPK + i];
        s_w[i]   = wgt[b_base * TOPK + i];
    }

    // stage 256 rows x 64 cols slab, float4
    for (int f = tid; f < MEMN * (COLS / 4); f += 256) {
        const int row = f >> 4;          // COLS/4 == 16 float4 per row
        const int c4  = f & 15;
        const float4 v = *reinterpret_cast<const float4*>(
            mem + (size_t)row * PROMPT + col_base + c4 * 4);
        *reinterpret_cast<float4*>(slab + row * COLS + c4 * 4) = v;
    }
    __syncthreads();

    const int col = tid & 63;       // wave-uniform batch, per-lane column
    const int bq  = tid >> 6;       // 0..3: which 16-batch group
    for (int bb = 0; bb < BT / 4; ++bb) {
        const int b = bq * (BT / 4) + bb;
        float acc = 0.f;
#pragma unroll
        for (int k = 0; k < TOPK; ++k) {
            const int   id = s_ids[b * TOPK + k];   // broadcast (wave-uniform)
            const float w  = s_w[b * TOPK + k];
            acc += w * slab[id * COLS + col];       // 2-way bank alias: free
        }
        out[(size_t)(b_base + b) * PROMPT + col_base + col] = acc;
    }
}

extern "C" void kernel_launch(void* const* d_in, const int* in_sizes, int n_in,
                              void* d_out, int out_size, void* d_ws, size_t ws_size,
                              hipStream_t stream) {
    const float* features = (const float*)d_in[0];   // (512, 512)
    const float* keys     = (const float*)d_in[1];   // (256, 512)
    const float* mem      = (const float*)d_in[2];   // (256, 131072)
    float* out = (float*)d_out;                      // (512, 131072)

    int*   ids = (int*)d_ws;                                    // 512*16 ints
    float* wgt = (float*)((char*)d_ws + BATCH * TOPK * sizeof(int));

    topk_kernel<<<BATCH, 256, 0, stream>>>(features, keys, ids, wgt);
    ctx_kernel<<<CHUNKS * TILES, 256, 0, stream>>>(mem, ids, wgt, out);
}

// Round 2
// 555.194 us; speedup vs baseline: 1.5577x; 1.5577x over previous
//
#include <hip/hip_runtime.h>

#define FEAT   512
#define MEMN   256
#define BATCH  512
#define PROMPT 131072   // 64*2048 flattened
#define TOPK   16
#define EPSF   1e-8f

// ctx tiling
#define CCOLS  32                 // columns per chunk (LDS slab width)
#define NCH    32                 // chunks per block (amortizes reg-resident ids)
#define NGRP   128                // column groups: 131072 / (CCOLS*NCH)
#define BT     64                 // batches per block
#define NTILE  8                  // 512 / BT

// ---------------------------------------------------------------------------
// Kernel A0: normalize keys -> kn (workspace). One block per key row.
// ---------------------------------------------------------------------------
__global__ __launch_bounds__(256) void knorm_kernel(
    const float* __restrict__ keys, float* __restrict__ kn)
{
    __shared__ float red[4];
    const int m = blockIdx.x;
    const int tid = threadIdx.x;
    float2 v = *reinterpret_cast<const float2*>(keys + m * FEAT + tid * 2);
    float p = v.x * v.x + v.y * v.y;
    for (int off = 32; off; off >>= 1) p += __shfl_down(p, off);
    if ((tid & 63) == 0) red[tid >> 6] = p;
    __syncthreads();
    float s = red[0] + red[1] + red[2] + red[3];
    float nrm = sqrtf(s); if (nrm < EPSF) nrm = EPSF;
    const float inv = 1.0f / nrm;
    float2 o; o.x = v.x * inv; o.y = v.y * inv;
    *reinterpret_cast<float2*>(kn + m * FEAT + tid * 2) = o;
}

// ---------------------------------------------------------------------------
// Kernel A: sim = (f/|f|) . kn^T, top-16, clamp+renorm weights.
// One block per batch. Sim phase: 16 lanes per key row, coalesced float4.
// ---------------------------------------------------------------------------
__global__ __launch_bounds__(256) void topk_kernel(
    const float* __restrict__ features,
    const float* __restrict__ kn,
    int* __restrict__ out_ids,
    float* __restrict__ out_w)
{
    __shared__ float f_lds[FEAT];
    __shared__ float sim_lds[MEMN];
    __shared__ float red[4];

    const int b = blockIdx.x;
    const int tid = threadIdx.x;

    // stage f + compute |f|^2
    float2 fv = *reinterpret_cast<const float2*>(features + b * FEAT + tid * 2);
    *reinterpret_cast<float2*>(f_lds + tid * 2) = fv;
    float p = fv.x * fv.x + fv.y * fv.y;
    for (int off = 32; off; off >>= 1) p += __shfl_down(p, off);
    if ((tid & 63) == 0) red[tid >> 6] = p;
    __syncthreads();
    const float f2 = red[0] + red[1] + red[2] + red[3];
    float fn = sqrtf(f2); if (fn < EPSF) fn = EPSF;
    const float invf = 1.0f / fn;

    // sim: wave handles 4 rows x 16 lanes each, 16 passes
    const int wave = tid >> 6, lane = tid & 63;
    const int jc = lane & 15, msub = lane >> 4;
    for (int pss = 0; pss < 16; ++pss) {
        const int m = pss * 16 + wave * 4 + msub;
        const float* krow = kn + m * FEAT;
        float dot = 0.f;
#pragma unroll
        for (int s = 0; s < 8; ++s) {
            float4 kv = *reinterpret_cast<const float4*>(krow + s * 64 + jc * 4);
            float4 fw = *reinterpret_cast<const float4*>(f_lds + s * 64 + jc * 4);
            dot += kv.x * fw.x + kv.y * fw.y + kv.z * fw.z + kv.w * fw.w;
        }
        dot += __shfl_xor(dot, 1); dot += __shfl_xor(dot, 2);
        dot += __shfl_xor(dot, 4); dot += __shfl_xor(dot, 8);
        if (jc == 0) sim_lds[m] = dot * invf;
    }
    __syncthreads();

    // single-wave top-16 (tie -> lowest index, matches jax.lax.top_k)
    if (tid < 64) {
        const int lane_ = tid;
        float v0 = sim_lds[lane_];
        float v1 = sim_lds[lane_ + 64];
        float v2 = sim_lds[lane_ + 128];
        float v3 = sim_lds[lane_ + 192];
        int myid = 0;

        for (int r = 0; r < TOPK; ++r) {
            float bv = v0; int bi = lane_;
            if (v1 > bv) { bv = v1; bi = lane_ + 64;  }
            if (v2 > bv) { bv = v2; bi = lane_ + 128; }
            if (v3 > bv) { bv = v3; bi = lane_ + 192; }
            for (int off = 32; off > 0; off >>= 1) {
                const float ov = __shfl_down(bv, off);
                const int   oi = __shfl_down(bi, off);
                if (ov > bv || (ov == bv && oi < bi)) { bv = ov; bi = oi; }
            }
            bi = __shfl(bi, 0);
            if (lane_ == r) myid = bi;
            if ((bi & 63) == lane_) {
                const int slot = bi >> 6;
                if      (slot == 0) v0 = -1e30f;
                else if (slot == 1) v1 = -1e30f;
                else if (slot == 2) v2 = -1e30f;
                else                v3 = -1e30f;
            }
        }

        if (lane_ < TOPK) {
            float val = sim_lds[myid];
            if (val < 0.f) val = 0.f;
            float s = val;
            for (int off = 1; off < TOPK; off <<= 1)
                s += __shfl_xor(s, off);
            out_ids[b * TOPK + lane_] = myid;
            out_w[b * TOPK + lane_]   = val / s;
        }
    }
}

// ---------------------------------------------------------------------------
// Kernel B: ctx[b, col] = sum_k w[b,k] * mem[id[b,k], col]
// Block: 64 batches x 32-col chunks, looping over 32 chunks so (id,w) stay
// in registers. Slab 32 KB (4 blocks/CU). Compute reads are ds_read_b128
// with uniform 8-per-bank distribution (== contiguous-pattern cost).
// Staging: global_load_lds width 16, lane-linear LDS (wave base + lane*16).
// ---------------------------------------------------------------------------
__global__ __launch_bounds__(256, 4) void ctx_kernel(
    const float* __restrict__ mem,
    const int* __restrict__ ids,
    const float* __restrict__ wgt,
    float* __restrict__ out)
{
    __shared__ float slab[MEMN * CCOLS];   // 32 KB

    const int bid  = blockIdx.x;
    const int xcd  = bid & 7;
    const int idx  = bid >> 3;
    const int tile = idx >> 4;                 // 0..7
    const int g    = xcd * 16 + (idx & 15);    // 0..127, tiles of a group co-XCD
    const int b_base = tile * BT;
    const int col0   = g * (NCH * CCOLS);      // 1024-col swath

    const int tid  = threadIdx.x;
    const int wave = tid >> 6, lane = tid & 63;
    const int bg   = lane >> 3;                // batch sub-group 0..7
    const int cg   = lane & 7;                 // col group 0..7 (4 floats each)

    const int b0 = b_base + wave * 16 + bg;
    const int b1 = b0 + 8;

    // (id, w) -> registers for the whole kernel; ids pre-scaled to LDS byte offs
    int   off0[TOPK], off1[TOPK];
    float w0[TOPK],  w1[TOPK];
#pragma unroll
    for (int q = 0; q < 4; ++q) {
        int4   i0 = *reinterpret_cast<const int4*>(ids + b0 * TOPK + q * 4);
        int4   i1 = *reinterpret_cast<const int4*>(ids + b1 * TOPK + q * 4);
        float4 v0 = *reinterpret_cast<const float4*>(wgt + b0 * TOPK + q * 4);
        float4 v1 = *reinterpret_cast<const float4*>(wgt + b1 * TOPK + q * 4);
        off0[q*4+0] = i0.x * (CCOLS*4) + cg * 16;
        off0[q*4+1] = i0.y * (CCOLS*4) + cg * 16;
        off0[q*4+2] = i0.z * (CCOLS*4) + cg * 16;
        off0[q*4+3] = i0.w * (CCOLS*4) + cg * 16;
        off1[q*4+0] = i1.x * (CCOLS*4) + cg * 16;
        off1[q*4+1] = i1.y * (CCOLS*4) + cg * 16;
        off1[q*4+2] = i1.z * (CCOLS*4) + cg * 16;
        off1[q*4+3] = i1.w * (CCOLS*4) + cg * 16;
        w0[q*4+0] = v0.x; w0[q*4+1] = v0.y; w0[q*4+2] = v0.z; w0[q*4+3] = v0.w;
        w1[q*4+0] = v1.x; w1[q*4+1] = v1.y; w1[q*4+2] = v1.z; w1[q*4+3] = v1.w;
    }

    const char* slb = reinterpret_cast<const char*>(slab);

    for (int c = 0; c < NCH; ++c) {
        const int cb = col0 + c * CCOLS;

        // stage 256 rows x 128 B; each wave: 8 iters x (8 rows x 128 B = 1 KB)
#pragma unroll
        for (int i = 0; i < 8; ++i) {
            const int r = wave * 64 + i * 8 + bg;
            const float* gp = mem + (size_t)r * PROMPT + cb + cg * 4;
            float* lp = slab + (size_t)(wave * 64 + i * 8) * CCOLS + lane * 4;
            __builtin_amdgcn_global_load_lds(
                (const __attribute__((address_space(1))) unsigned int*)gp,
                (__attribute__((address_space(3))) unsigned int*)lp,
                16, 0, 0);
        }
        __syncthreads();

        float4 acc;
        acc.x = acc.y = acc.z = acc.w = 0.f;
#pragma unroll
        for (int k = 0; k < TOPK; ++k) {
            const float4 v = *reinterpret_cast<const float4*>(slb + off0[k]);
            acc.x += w0[k] * v.x; acc.y += w0[k] * v.y;
            acc.z += w0[k] * v.z; acc.w += w0[k] * v.w;
        }
        *reinterpret_cast<float4*>(out + (size_t)b0 * PROMPT + cb + cg * 4) = acc;

        acc.x = acc.y = acc.z = acc.w = 0.f;
#pragma unroll
        for (int k = 0; k < TOPK; ++k) {
            const float4 v = *reinterpret_cast<const float4*>(slb + off1[k]);
            acc.x += w1[k] * v.x; acc.y += w1[k] * v.y;
            acc.z += w1[k] * v.z; acc.w += w1[k] * v.w;
        }
        *reinterpret_cast<float4*>(out + (size_t)b1 * PROMPT + cb + cg * 4) = acc;

        __syncthreads();   // slab reused next chunk
    }
}

extern "C" void kernel_launch(void* const* d_in, const int* in_sizes, int n_in,
                              void* d_out, int out_size, void* d_ws, size_t ws_size,
                              hipStream_t stream) {
    const float* features = (const float*)d_in[0];   // (512, 512)
    const float* keys     = (const float*)d_in[1];   // (256, 512)
    const float* mem      = (const float*)d_in[2];   // (256, 131072)
    float* out = (float*)d_out;                      // (512, 131072)

    char* ws = (char*)d_ws;
    int*   ids = (int*)ws;                               // 32 KB
    float* wgt = (float*)(ws + 32768);                   // 32 KB
    float* kn  = (float*)(ws + 65536);                   // 512 KB

    knorm_kernel<<<MEMN, 256, 0, stream>>>(keys, kn);
    topk_kernel<<<BATCH, 256, 0, stream>>>(features, kn, ids, wgt);
    ctx_kernel<<<NTILE * NGRP, 256, 0, stream>>>(mem, ids, wgt, out);
}